// Round 6
// baseline (192.040 us; speedup 1.0000x reference)
//
#include <hip/hip_runtime.h>

// Sobel 3D magnitude, separable: S=[1,2,1], D=[1,0,-1]
// gx = Sz(Sy(Dx)), gy = Sz(Dy(Sx)), gz = Dz(Sy(Sx)); out = sqrt(gx^2+gy^2+gz^2+1e-6)
// x: (2,32,64,128,128) fp32.
// R6: R5 (no LDS, no barriers, register rolling window) + depth-2 prefetch:
// two in-flight row-triples p (odd planes) / q (even planes), consumed in a
// 2-half loop body so every load has ~2x the latency-hiding distance.
// Plus XCD-contiguous block remap (2048 = 8 x 256) for halo L2 locality.

typedef float floatx4 __attribute__((ext_vector_type(4)));

constexpr int W   = 128;
constexpr int H   = 128;
constexpr int DZ  = 64;
constexpr int NC  = 2 * 32;
constexpr int TH  = 8;            // output rows per block
constexpr int HBLKS = H / TH;     // 16
constexpr int ZCH = 2;            // z chunks (ZLEN must be even)
constexpr int ZLEN = DZ / ZCH;    // 32
constexpr int NWG = NC * ZCH * HBLKS;   // 2048
constexpr int NXCD = 8;
constexpr int WPX = NWG / NXCD;   // 256

__global__ __launch_bounds__(256, 6)
void sobel3d_kernel(const float* __restrict__ xg, float* __restrict__ og) {
    const int tid = threadIdx.x;
    const int tx  = tid & 31;      // w segment: pixels 4*tx..4*tx+3
    const int ty  = tid >> 5;      // row 0..7 within tile
    // XCD-contiguous remap: hardware round-robins dispatch index across 8 XCDs;
    // give XCD k the contiguous logical range [k*256, (k+1)*256).
    int b = (blockIdx.x & (NXCD - 1)) * WPX + (blockIdx.x >> 3);
    const int hblk = b % HBLKS; b /= HBLKS;
    const int zc   = b % ZCH;   b /= ZCH;
    const int nc   = b;
    const int h    = hblk * TH + ty;   // this thread's output row
    const int za   = zc * ZLEN;
    const int zb   = za + ZLEN;        // exclusive; plane zb is last needed

    const float* __restrict__ xp = xg + (size_t)nc * DZ * H * W;
    float* __restrict__ op       = og + (size_t)nc * DZ * H * W;

    const bool hm = (h > 0);
    const bool hp = (h < H - 1);
    const size_t roff = (size_t)h * W + 4 * tx;

    // load rows h-1,h,h+1 of plane z (z out of [0,DZ) -> zeros, no memory op)
    auto gload3 = [&](int z, floatx4& a, floatx4& bq, floatx4& c) {
        if ((unsigned)z < (unsigned)DZ) {
            const float* p = xp + (size_t)z * H * W + roff;
            a  = hm ? *(const floatx4*)(p - W) : (floatx4){0.f, 0.f, 0.f, 0.f};
            bq = *(const floatx4*)p;
            c  = hp ? *(const floatx4*)(p + W) : (floatx4){0.f, 0.f, 0.f, 0.f};
        } else {
            a = bq = c = (floatx4){0.f, 0.f, 0.f, 0.f};
        }
    };

    // horizontal pass on one row: Sx, Dx (w-halo via intra-wave shuffles)
    auto row_sd = [&](floatx4 q, floatx4& s, floatx4& d) {
        float xm1 = __shfl_up(q.w, 1, 64);
        if (tx == 0)  xm1 = 0.f;
        float xp4 = __shfl_down(q.x, 1, 64);
        if (tx == 31) xp4 = 0.f;
        s.x = xm1 + 2.f * q.x + q.y;
        s.y = q.x + 2.f * q.y + q.z;
        s.z = q.y + 2.f * q.z + q.w;
        s.w = q.z + 2.f * q.w + xp4;
        d.x = xm1 - q.y;
        d.y = q.x - q.z;
        d.z = q.y - q.w;
        d.w = q.z - xp4;
    };

    // full xy pass: cc=Sy(Sx), dd=Dy(Sx), ee=Sy(Dx)
    auto plane_sde = [&](floatx4 qA, floatx4 qB, floatx4 qC,
                         floatx4& cc, floatx4& dd, floatx4& ee) {
        floatx4 s, d;
        row_sd(qA, s, d); cc = s;       dd = s;  ee = d;
        row_sd(qB, s, d); cc += 2.f * s;         ee += 2.f * d;
        row_sd(qC, s, d); cc += s;      dd -= s; ee += d;
    };

    // rolling 2-plane intermediates: P = plane z-1, C = plane z
    floatx4 cP, dP, eP, cC, dCv, eC;
    {
        floatx4 a, bq, c;
        gload3(za - 1, a, bq, c); plane_sde(a, bq, c, cP, dP, eP);
        gload3(za,     a, bq, c); plane_sde(a, bq, c, cC, dCv, eC);
    }
    // depth-2 raw-row prefetch: p holds odd-offset planes, q even-offset
    floatx4 pA, pB, pC, qA, qB, qC;
    gload3(za + 1, pA, pB, pC);
    gload3(za + 2, qA, qB, qC);

    size_t obase = (size_t)za * H * W + roff;
    const size_t ostep = (size_t)H * W;

    auto emit = [&](floatx4 c2, floatx4 d2, floatx4 e2) {
        floatx4 gx = eP + 2.f * eC + e2;
        floatx4 gy = dP + 2.f * dCv + d2;
        floatx4 gz = cP - c2;
        floatx4 o;
        o.x = __builtin_amdgcn_sqrtf(gx.x * gx.x + gy.x * gy.x + gz.x * gz.x + 1e-6f);
        o.y = __builtin_amdgcn_sqrtf(gx.y * gx.y + gy.y * gy.y + gz.y * gz.y + 1e-6f);
        o.z = __builtin_amdgcn_sqrtf(gx.z * gx.z + gy.z * gy.z + gz.z * gz.z + 1e-6f);
        o.w = __builtin_amdgcn_sqrtf(gx.w * gx.w + gy.w * gy.w + gz.w * gz.w + 1e-6f);
        __builtin_nontemporal_store(o, (floatx4*)(op + obase));
        // roll the intermediate window
        cP = cC;  cC  = c2;
        dP = dCv; dCv = d2;
        eP = eC;  eC  = e2;
        obase += ostep;
    };

    for (int z = za; z < zb; z += 2) {
        // half A: emit plane z (consumes p = rows of z+1), prefetch z+3 -> p
        {
            int zn = z + 3;
            if (zn > zb) zn = DZ;              // beyond need -> zeros, no fetch
            floatx4 nA, nB, nC;
            gload3(zn, nA, nB, nC);
            floatx4 c2, d2, e2;
            plane_sde(pA, pB, pC, c2, d2, e2);
            emit(c2, d2, e2);
            pA = nA; pB = nB; pC = nC;
        }
        // half B: emit plane z+1 (consumes q = rows of z+2), prefetch z+4 -> q
        {
            int zn = z + 4;
            if (zn > zb) zn = DZ;
            floatx4 mA, mB, mC;
            gload3(zn, mA, mB, mC);
            floatx4 c2, d2, e2;
            plane_sde(qA, qB, qC, c2, d2, e2);
            emit(c2, d2, e2);
            qA = mA; qB = mB; qC = mC;
        }
    }
}

extern "C" void kernel_launch(void* const* d_in, const int* in_sizes, int n_in,
                              void* d_out, int out_size, void* d_ws, size_t ws_size,
                              hipStream_t stream) {
    const float* x = (const float*)d_in[0];
    float* out = (float*)d_out;
    dim3 grid(NWG);   // 2048 blocks == full 8-blocks/CU residency
    dim3 block(256);
    sobel3d_kernel<<<grid, block, 0, stream>>>(x, out);
}

// Round 7
// 96.627 us; speedup vs baseline: 1.9874x; 1.9874x over previous
//
#include <hip/hip_runtime.h>

// Sobel 3D magnitude, separable: S=[1,2,1], D=[1,0,-1]
// gx = Sz(Sy(Dx)), gy = Sz(Dy(Sx)), gz = Dz(Sy(Sx)); out = sqrt(gx^2+gy^2+gz^2+1e-6)
// x: (2,32,64,128,128) fp32.
// R7 = R5 structure (no LDS, no barriers, depth-1 prefetch, single body/emit)
// + VALU diet: y-pass-first separable order (4 shuffles/plane instead of 6,
// Dx reuses Sx halos), marching pointers (no per-iter z*H*W), wave-uniform
// scalar branch for the prefetch validity instead of per-lane clamps.

typedef float floatx4 __attribute__((ext_vector_type(4)));

constexpr int W   = 128;
constexpr int H   = 128;
constexpr int DZ  = 64;
constexpr int NC  = 2 * 32;
constexpr int TH  = 8;            // output rows per block
constexpr int HBLKS = H / TH;     // 16
constexpr int ZCH = 2;            // z chunks
constexpr int ZLEN = DZ / ZCH;    // 32

__global__ __launch_bounds__(256, 6)
void sobel3d_kernel(const float* __restrict__ xg, float* __restrict__ og) {
    const int tid = threadIdx.x;
    const int tx  = tid & 31;      // w segment: pixels 4*tx..4*tx+3
    const int ty  = tid >> 5;      // row 0..7 within tile
    int b = blockIdx.x;
    const int hblk = b % HBLKS; b /= HBLKS;
    const int zc   = b % ZCH;   b /= ZCH;
    const int nc   = b;
    const int h    = hblk * TH + ty;
    const int za   = zc * ZLEN;
    const int zb   = za + ZLEN;                  // exclusive
    const int lastv = (zb < DZ) ? zb : DZ - 1;   // last loadable plane index

    const size_t HW = (size_t)H * W;
    const float* __restrict__ xp = xg + (size_t)nc * DZ * HW;
    float* __restrict__ op       = og + (size_t)nc * DZ * HW;

    const bool hm = (h > 0);
    const bool hp = (h < H - 1);
    const size_t roff = (size_t)h * W + 4 * tx;

    // rows h-1,h,h+1 at pointer p (p = plane base + roff); ±W fold to imm offsets
    auto load3 = [&](const float* p, floatx4& a, floatx4& bq, floatx4& c) {
        a  = hm ? *(const floatx4*)(p - W) : (floatx4){0.f, 0.f, 0.f, 0.f};
        bq = *(const floatx4*)p;
        c  = hp ? *(const floatx4*)(p + W) : (floatx4){0.f, 0.f, 0.f, 0.f};
    };

    // y-pass first (no shuffles), then x-pass on u=Sy(x), v=Dy(x).
    // cc = Sx(Sy), dd = Sx(Dy) = Dy(Sx), ee = Dx(Sy) = Sy(Dx)  (axes commute)
    auto plane_sde = [&](floatx4 qA, floatx4 qB, floatx4 qC,
                         floatx4& cc, floatx4& dd, floatx4& ee) {
        floatx4 u = qA + 2.f * qB + qC;
        floatx4 v = qA - qC;
        float um1 = __shfl_up(u.w, 1, 64);   if (tx == 0)  um1 = 0.f;
        float up4 = __shfl_down(u.x, 1, 64); if (tx == 31) up4 = 0.f;
        float vm1 = __shfl_up(v.w, 1, 64);   if (tx == 0)  vm1 = 0.f;
        float vp4 = __shfl_down(v.x, 1, 64); if (tx == 31) vp4 = 0.f;
        cc.x = um1 + 2.f * u.x + u.y;
        cc.y = u.x + 2.f * u.y + u.z;
        cc.z = u.y + 2.f * u.z + u.w;
        cc.w = u.z + 2.f * u.w + up4;
        ee.x = um1 - u.y;                 // Dx(u): reuses u's shuffled halos
        ee.y = u.x - u.z;
        ee.z = u.y - u.w;
        ee.w = u.z - up4;
        dd.x = vm1 + 2.f * v.x + v.y;
        dd.y = v.x + 2.f * v.y + v.z;
        dd.z = v.y + 2.f * v.z + v.w;
        dd.w = v.z + 2.f * v.w + vp4;
    };

    // rolling 2-plane intermediates: P = plane z-1, C = plane z
    floatx4 cP, dP, eP, cC, dCv, eC;
    const float* pin = xp + (size_t)za * HW + roff;   // plane za
    {
        floatx4 a, bq, c;
        if (za > 0) { load3(pin - HW, a, bq, c); plane_sde(a, bq, c, cP, dP, eP); }
        else        { cP = dP = eP = (floatx4){0.f, 0.f, 0.f, 0.f}; }
        load3(pin, a, bq, c); plane_sde(a, bq, c, cC, dCv, eC);
    }
    // depth-1 prefetch: raw rows of plane za+1 (always valid: za+1 <= 33 < DZ)
    floatx4 pA, pB, pC;
    load3(pin + HW, pA, pB, pC);
    pin += 2 * HW;                                    // -> plane za+2
    float* pout = op + (size_t)za * HW + roff;

#pragma unroll 2
    for (int z = za; z < zb; ++z) {
        // prefetch plane z+2 (wave-uniform validity -> scalar branch, no fetch past need)
        floatx4 nA, nB, nC;
        if (z + 2 <= lastv) load3(pin, nA, nB, nC);
        else { nA = nB = nC = (floatx4){0.f, 0.f, 0.f, 0.f}; }
        pin += HW;

        // compute plane z+1 intermediates from rows prefetched last iteration
        floatx4 c2, d2, e2;
        plane_sde(pA, pB, pC, c2, d2, e2);

        // emit output plane z
        floatx4 gx = eP + 2.f * eC + e2;
        floatx4 gy = dP + 2.f * dCv + d2;
        floatx4 gz = cP - c2;
        floatx4 o;
        o.x = __builtin_amdgcn_sqrtf(gx.x * gx.x + gy.x * gy.x + gz.x * gz.x + 1e-6f);
        o.y = __builtin_amdgcn_sqrtf(gx.y * gx.y + gy.y * gy.y + gz.y * gz.y + 1e-6f);
        o.z = __builtin_amdgcn_sqrtf(gx.z * gx.z + gy.z * gy.z + gz.z * gz.z + 1e-6f);
        o.w = __builtin_amdgcn_sqrtf(gx.w * gx.w + gy.w * gy.w + gz.w * gz.w + 1e-6f);
        __builtin_nontemporal_store(o, (floatx4*)pout);
        pout += HW;

        // roll windows (renamed away by the unroll)
        cP = cC;  cC  = c2;
        dP = dCv; dCv = d2;
        eP = eC;  eC  = e2;
        pA = nA;  pB  = nB;  pC = nC;
    }
}

extern "C" void kernel_launch(void* const* d_in, const int* in_sizes, int n_in,
                              void* d_out, int out_size, void* d_ws, size_t ws_size,
                              hipStream_t stream) {
    const float* x = (const float*)d_in[0];
    float* out = (float*)d_out;
    dim3 grid(NC * ZCH * HBLKS);   // 2048 blocks == full 8-blocks/CU residency
    dim3 block(256);
    sobel3d_kernel<<<grid, block, 0, stream>>>(x, out);
}